// Round 12
// baseline (356.508 us; speedup 1.0000x reference)
//
#include <hip/hip_runtime.h>
#include <hip/hip_cooperative_groups.h>
#include <math.h>
#include <stdint.h>

namespace cg = cooperative_groups;

#define N 4096
#define Dm 1024
#define BK 64
#define NT (Dm / BK)   // 16 K-tiles
#define NCB (N / 64)   // 64 column-partials per row

typedef __attribute__((ext_vector_type(8))) short bf16x8;
typedef __attribute__((ext_vector_type(4))) float f32x4;

typedef const void __attribute__((address_space(1)))* gas_t;
typedef void __attribute__((address_space(3)))* las_t;

static __device__ __forceinline__ void gload_lds16(const void* g, void* l) {
    // async global->LDS, 16B per lane; LDS dest is wave-uniform base + lane*16
    __builtin_amdgcn_global_load_lds((gas_t)g, (las_t)l, 16, 0, 0);
}

static __device__ __forceinline__ unsigned short f2bf(float f) {
    unsigned int u = __float_as_uint(f);
    unsigned int r = (u + 0x7fff + ((u >> 16) & 1)) >> 16;  // RNE
    return (unsigned short)r;
}

// ---------------------------------------------------------------------------
// FUSED cooperative kernel (R10, resubmitted): prep -> grid.sync -> 256x256
// MFMA GEMM with fused flash epilogue (R8 body, byte-preserved) -> grid.sync
// -> combine -> grid.sync -> block0 final. 256 blocks x 512 thr = 1 block/CU
// (128 KB LDS), co-residency guaranteed by cooperative launch. __threadfence()
// before each sync publishes cross-XCD (Guideline 16); grid.sync's device-
// scope acquire handles reader-side invalidation.
//
// GEMM invariants (unchanged from R8, hand-verified):
//  vmem queue entering tile t: [B(t+1) x4]; ph0 +A(t+1), ph1/2 +B(t+2) x2+2;
//  ph3 vmcnt(4) completes B(t+1)+A(t+1) BEFORE the barrier; refill reads are
//  pinned below it by sched_barrier(0). t==14: vmcnt(0); t==15: none.
//  Explicit vmcnt(0)+lgkmcnt(0) drain after sync#1 -> counted region starts
//  clean. LDS WAR separations >=2 barriers. All guards block-uniform.
// ---------------------------------------------------------------------------
#define STAGE_TILE(gp, lp, kt) do {                                            \
        gload_lds16((gp) + (kt),                    (lp)         + tid * 8);   \
        gload_lds16((gp) + (kt) +  64 * (size_t)Dm, (lp) + 4096  + tid * 8);   \
        gload_lds16((gp) + (kt) + 128 * (size_t)Dm, (lp) + 8192  + tid * 8);   \
        gload_lds16((gp) + (kt) + 192 * (size_t)Dm, (lp) + 12288 + tid * 8);   \
    } while (0)

#define STAGE_B_HALF(lpB, kt, h) do {                                          \
        gload_lds16(gB + (kt) + ((h) ? 128 * (size_t)Dm : (size_t)0),          \
                    (lpB) + (h) * 8192 + tid * 8);                             \
        gload_lds16(gB + (kt) + ((h) ? 192 * (size_t)Dm : 64 * (size_t)Dm),    \
                    (lpB) + (h) * 8192 + 4096 + tid * 8);                      \
    } while (0)

#define READ_A4(dst, buf, rg0) do {                                            \
        dst[0] = *(const bf16x8*)((buf) + ((rg0)     * 16) * BK + aoff0);      \
        dst[1] = *(const bf16x8*)((buf) + ((rg0)     * 16) * BK + aoff1);      \
        dst[2] = *(const bf16x8*)((buf) + ((rg0) + 1) * 16 * BK + aoff0);      \
        dst[3] = *(const bf16x8*)((buf) + ((rg0) + 1) * 16 * BK + aoff1);      \
    } while (0)

#define READ_B8(buf) do {                                                      \
        _Pragma("unroll")                                                      \
        for (int j = 0; j < 4; ++j) {                                          \
            bfr[j][0] = *(const bf16x8*)((buf) + j * 16 * BK + aoff0);         \
            bfr[j][1] = *(const bf16x8*)((buf) + j * 16 * BK + aoff1);         \
        }                                                                      \
    } while (0)

#define MFMA_PH(P, ap)                                                         \
    _Pragma("unroll")                                                          \
    for (int j = 0; j < 4; ++j)                                                \
        acc[2*(P)][j]   = __builtin_amdgcn_mfma_f32_16x16x32_bf16(ap[0], bfr[j][0], acc[2*(P)][j],   0, 0, 0); \
    _Pragma("unroll")                                                          \
    for (int j = 0; j < 4; ++j)                                                \
        acc[2*(P)][j]   = __builtin_amdgcn_mfma_f32_16x16x32_bf16(ap[1], bfr[j][1], acc[2*(P)][j],   0, 0, 0); \
    _Pragma("unroll")                                                          \
    for (int j = 0; j < 4; ++j)                                                \
        acc[2*(P)+1][j] = __builtin_amdgcn_mfma_f32_16x16x32_bf16(ap[2], bfr[j][0], acc[2*(P)+1][j], 0, 0, 0); \
    _Pragma("unroll")                                                          \
    for (int j = 0; j < 4; ++j)                                                \
        acc[2*(P)+1][j] = __builtin_amdgcn_mfma_f32_16x16x32_bf16(ap[3], bfr[j][1], acc[2*(P)+1][j], 0, 0, 0);

// ph3 cluster, j-outer: after bfr[j]'s 4th (last) use, refill it for tile NXT.
#define MFMA_PH3_REFILL(ap, bufn, DOREFILL)                                    \
    _Pragma("unroll")                                                          \
    for (int j = 0; j < 4; ++j) {                                              \
        acc[6][j] = __builtin_amdgcn_mfma_f32_16x16x32_bf16(ap[0], bfr[j][0], acc[6][j], 0, 0, 0); \
        acc[6][j] = __builtin_amdgcn_mfma_f32_16x16x32_bf16(ap[1], bfr[j][1], acc[6][j], 0, 0, 0); \
        acc[7][j] = __builtin_amdgcn_mfma_f32_16x16x32_bf16(ap[2], bfr[j][0], acc[7][j], 0, 0, 0); \
        acc[7][j] = __builtin_amdgcn_mfma_f32_16x16x32_bf16(ap[3], bfr[j][1], acc[7][j], 0, 0, 0); \
        if (DOREFILL) {                                                        \
            bfr[j][0] = *(const bf16x8*)((bufn) + j * 16 * BK + aoff0);        \
            bfr[j][1] = *(const bf16x8*)((bufn) + j * 16 * BK + aoff1);        \
        }                                                                      \
    }

#define PHASE_EDGE() do {                                                      \
        __builtin_amdgcn_sched_barrier(0);                                     \
        __builtin_amdgcn_s_barrier();                                          \
        asm volatile("s_waitcnt lgkmcnt(0)" ::: "memory");                     \
        __builtin_amdgcn_sched_barrier(0);                                     \
    } while (0)

#define TILE_BODY(CUR, NXT) do {                                               \
        const unsigned short* aT  = aBase + (CUR) * 16384;                     \
        const unsigned short* aTn = aBase + (NXT) * 16384;                     \
        const unsigned short* bTn = bBase + (NXT) * 16384;                     \
        unsigned short* stA = &As[NXT][0];                                     \
        unsigned short* stB = &Bs[CUR][0];                                     \
        READ_A4(aF[1], aT, 2);                                                 \
        if (t >= 1 && t <= 14) STAGE_TILE(gA, stA, (t + 1) * BK);              \
        __builtin_amdgcn_s_setprio(1);                                         \
        MFMA_PH(0, aF[0])                                                      \
        __builtin_amdgcn_s_setprio(0);                                         \
        PHASE_EDGE();                                                          \
        READ_A4(aF[0], aT, 4);                                                 \
        if (t <= 13) STAGE_B_HALF(stB, (t + 2) * BK, 0);                       \
        __builtin_amdgcn_s_setprio(1);                                         \
        MFMA_PH(1, aF[1])                                                      \
        __builtin_amdgcn_s_setprio(0);                                         \
        PHASE_EDGE();                                                          \
        READ_A4(aF[1], aT, 6);                                                 \
        if (t <= 13) STAGE_B_HALF(stB, (t + 2) * BK, 1);                       \
        __builtin_amdgcn_s_setprio(1);                                         \
        MFMA_PH(2, aF[0])                                                      \
        __builtin_amdgcn_s_setprio(0);                                         \
        PHASE_EDGE();                                                          \
        if (t <= 13)      { asm volatile("s_waitcnt vmcnt(4)" ::: "memory"); } \
        else if (t == 14) { asm volatile("s_waitcnt vmcnt(0)" ::: "memory"); } \
        if (t <= 14) __builtin_amdgcn_s_barrier();                             \
        __builtin_amdgcn_sched_barrier(0);                                     \
        __builtin_amdgcn_s_setprio(1);                                         \
        MFMA_PH3_REFILL(aF[1], bTn, (t <= 14))                                 \
        __builtin_amdgcn_s_setprio(0);                                         \
        if (t <= 14) {                                                         \
            READ_A4(aF[0], aTn, 0);                                            \
            PHASE_EDGE();                                                      \
        }                                                                      \
    } while (0)

__global__ __launch_bounds__(512, 2) void fused_npair(const float* __restrict__ A,
                                                      const float* __restrict__ P,
                                                      unsigned short* __restrict__ Abf,
                                                      unsigned short* __restrict__ Pbf,
                                                      float* __restrict__ D,
                                                      float* __restrict__ rowl2,
                                                      float* __restrict__ accL,
                                                      float* __restrict__ accR,
                                                      float* __restrict__ Mpart,
                                                      float* __restrict__ Spart,
                                                      float* __restrict__ out) {
    __shared__ unsigned short As[2][256 * BK];   // 64 KB
    __shared__ unsigned short Bs[2][256 * BK];   // 64 KB — 128 KB total, 1 block/CU

    cg::grid_group grid = cg::this_grid();

    int tid = threadIdx.x;
    int lane = tid & 63;
    int wid = tid >> 6;
    int bid = blockIdx.x;                        // 1-D grid [0,256)

    // ===== Section 1: prep — 16 rows/block, 2 rows/wave =====================
    if (bid == 0 && tid == 0) { accL[0] = 0.0f; accR[0] = 0.0f; }
#pragma unroll
    for (int r = 0; r < 2; ++r) {
        int row = bid * 16 + wid * 2 + r;
        const float4* a4 = (const float4*)(A + (size_t)row * Dm);
        const float4* p4 = (const float4*)(P + (size_t)row * Dm);
        ushort4* ao = (ushort4*)(Abf + (size_t)row * Dm);
        ushort4* po = (ushort4*)(Pbf + (size_t)row * Dm);
        float dot = 0.0f, l2 = 0.0f;
#pragma unroll
        for (int c = 0; c < 4; ++c) {
            int idx = c * 64 + lane;             // coalesced within the wave
            float4 a = a4[idx], p = p4[idx];
            ushort4 ab, pb;
            ab.x = f2bf(a.x); ab.y = f2bf(a.y); ab.z = f2bf(a.z); ab.w = f2bf(a.w);
            pb.x = f2bf(p.x); pb.y = f2bf(p.y); pb.z = f2bf(p.z); pb.w = f2bf(p.w);
            ao[idx] = ab; po[idx] = pb;
            dot += a.x * p.x + a.y * p.y + a.z * p.z + a.w * p.w;
            l2  += a.x * a.x + a.y * a.y + a.z * a.z + a.w * a.w
                 + p.x * p.x + p.y * p.y + p.z * p.z + p.w * p.w;
        }
#pragma unroll
        for (int off = 32; off; off >>= 1) {
            dot += __shfl_xor(dot, off, 64);
            l2  += __shfl_xor(l2,  off, 64);
        }
        if (lane == 0) { D[row] = dot; rowl2[row] = l2; }
    }
    __threadfence();                              // publish across XCD L2s
    grid.sync();

    // ===== Section 2: GEMM + flash epilogue (R8 body) =======================
    asm volatile("s_waitcnt vmcnt(0) lgkmcnt(0)" ::: "memory");  // clean counters
    __builtin_amdgcn_sched_barrier(0);

    int wr = wid >> 2, wc = wid & 3;             // 2x4 waves, 128x64 out each

    // XCD-aware bijective swizzle: 256 blocks -> 8 XCDs x 32.
    int xcd = bid & 7, lid = bid >> 3;
    int by = (xcd >> 1) * 4 + (lid >> 3);        // [0,16)
    int bx = (xcd & 1) * 8 + (lid & 7);          // [0,16)
    int row0 = by * 256, col0 = bx * 256;

    int srow = tid >> 3;
    int kcol = (tid & 7) ^ (srow & 7);
    const unsigned short* gA = Abf + (size_t)(row0 + srow) * Dm + (kcol << 3);
    const unsigned short* gB = Pbf + (size_t)(col0 + srow) * Dm + (kcol << 3);

    STAGE_TILE(gA, &As[0][0], 0);
    STAGE_TILE(gB, &Bs[0][0], 0);
    STAGE_TILE(gA, &As[1][0], BK);
    STAGE_TILE(gB, &Bs[1][0], BK);
    asm volatile("s_waitcnt vmcnt(8)" ::: "memory");
    __builtin_amdgcn_s_barrier();

    int l15 = lane & 15;
    int aoff0 = (((lane >> 4)    ) ^ (lane & 7)) << 3;
    int aoff1 = (((lane >> 4) + 4) ^ (lane & 7)) << 3;
    const unsigned short* aBase = &As[0][0] + (wr * 128 + l15) * BK;
    const unsigned short* bBase = &Bs[0][0] + (wc * 64  + l15) * BK;

    f32x4 acc[8][4] = {};
    bf16x8 bfr[4][2];
    bf16x8 aF[2][4];

    READ_B8(bBase);
    READ_A4(aF[0], aBase, 0);
    __builtin_amdgcn_sched_barrier(0);
    asm volatile("s_waitcnt lgkmcnt(0)" ::: "memory");
    __builtin_amdgcn_sched_barrier(0);

    for (int tt = 0; tt < NT / 2; ++tt) {
        int t = 2 * tt;
        TILE_BODY(0, 1);
        t = 2 * tt + 1;
        TILE_BODY(1, 0);
    }
    __builtin_amdgcn_sched_barrier(0);

    // Epilogue: partials of RAW S (shift-invariant LSE; D applied in combine).
    int cb = bx * 4 + wc;
#pragma unroll
    for (int i = 0; i < 8; ++i) {
        int rloc = wr * 128 + i * 16 + ((lane >> 4) << 2);
#pragma unroll
        for (int e = 0; e < 4; ++e) {
            int gr = row0 + rloc + e;
            float xs[4];
            float m = -INFINITY;
#pragma unroll
            for (int j = 0; j < 4; ++j) {
                int gc = col0 + wc * 64 + j * 16 + (lane & 15);
                float x = acc[i][j][e];
                if (gr == gc) x = -INFINITY;      // mask diagonal
                xs[j] = x;
                m = fmaxf(m, x);
            }
#pragma unroll
            for (int off = 8; off; off >>= 1) m = fmaxf(m, __shfl_xor(m, off, 64));
            float s = 0.0f;
#pragma unroll
            for (int j = 0; j < 4; ++j) s += __expf(xs[j] - m);
#pragma unroll
            for (int off = 8; off; off >>= 1) s += __shfl_xor(s, off, 64);
            if ((lane & 15) == 0) {
                Mpart[(size_t)gr * NCB + cb] = m;
                Spart[(size_t)gr * NCB + cb] = s;
            }
        }
    }
    __threadfence();                              // publish Mpart/Spart
    grid.sync();

    // ===== Section 3: combine — 16 rows/block, 2 rows/wave ==================
    float* ls = (float*)&As[0][0];               // As dead; reuse 64 B of LDS
#pragma unroll
    for (int r = 0; r < 2; ++r) {
        int row = bid * 16 + wid * 2 + r;
        float mp = Mpart[(size_t)row * NCB + lane];
        float sp = Spart[(size_t)row * NCB + lane];
        float m = mp;
#pragma unroll
        for (int off = 32; off; off >>= 1) m = fmaxf(m, __shfl_xor(m, off, 64));
        float s = sp * __expf(mp - m);
#pragma unroll
        for (int off = 32; off; off >>= 1) s += __shfl_xor(s, off, 64);
        if (lane == 0) {
            float z = m + logf(s) - D[row];      // LSE_offdiag(S) - D
            ls[wid * 2 + r] = fmaxf(z, 0.0f) + log1pf(__expf(-fabsf(z)));
        }
    }
    __syncthreads();
    if (tid == 0) {
        float L = 0.0f, R = 0.0f;
#pragma unroll
        for (int r = 0; r < 16; ++r) { L += ls[r]; R += rowl2[bid * 16 + r]; }
        atomicAdd(accL, L);
        atomicAdd(accR, R);
    }
    __threadfence();
    grid.sync();

    // ===== Section 4: final scalar ==========================================
    if (bid == 0 && tid == 0) {
        float aL = atomicAdd(accL, 0.0f);        // coherent device-scope read
        float aR = atomicAdd(accR, 0.0f);
        out[0] = aL / (float)N + 0.02f * (aR / (float)N);
    }
}

extern "C" void kernel_launch(void* const* d_in, const int* in_sizes, int n_in,
                              void* d_out, int out_size, void* d_ws, size_t ws_size,
                              hipStream_t stream) {
    const float* A = (const float*)d_in[0];
    const float* P = (const float*)d_in[1];
    float* out = (float*)d_out;

    unsigned short* Abf = (unsigned short*)d_ws;            // N*Dm bf16 = 8 MiB
    unsigned short* Pbf = Abf + (size_t)N * Dm;             // 8 MiB
    float* D     = (float*)(Pbf + (size_t)N * Dm);          // N
    float* rowl2 = D + N;                                   // N
    float* accL  = rowl2 + N;                               // 1
    float* accR  = accL + 1;                                // 1
    float* Mpart = accR + 1;                                // N*NCB = 1 MiB
    float* Spart = Mpart + (size_t)N * NCB;                 // 1 MiB

    void* args[] = { (void*)&A, (void*)&P, (void*)&Abf, (void*)&Pbf,
                     (void*)&D, (void*)&rowl2, (void*)&accL, (void*)&accR,
                     (void*)&Mpart, (void*)&Spart, (void*)&out };
    hipLaunchCooperativeKernel((void*)fused_npair, dim3(256), dim3(512),
                               args, 0, stream);
}

// Round 13
// 134.559 us; speedup vs baseline: 2.6495x; 2.6495x over previous
//
#include <hip/hip_runtime.h>
#include <math.h>
#include <stdint.h>

#define N 4096
#define Dm 1024
#define BK 64
#define NT (Dm / BK)   // 16 K-tiles
#define NCB (N / 64)   // 64 column-partials per row
#define NPART 512      // combine blocks

typedef __attribute__((ext_vector_type(8))) short bf16x8;
typedef __attribute__((ext_vector_type(4))) float f32x4;

typedef const void __attribute__((address_space(1)))* gas_t;
typedef void __attribute__((address_space(3)))* las_t;

static __device__ __forceinline__ void gload_lds16(const void* g, void* l) {
    // async global->LDS, 16B per lane; LDS dest is wave-uniform base + lane*16
    __builtin_amdgcn_global_load_lds((gas_t)g, (las_t)l, 16, 0, 0);
}

static __device__ __forceinline__ unsigned short f2bf(float f) {
    unsigned int u = __float_as_uint(f);
    unsigned int r = (u + 0x7fff + ((u >> 16) & 1)) >> 16;  // RNE
    return (unsigned short)r;
}

// Kernel 1: convert A,P -> bf16 + per-row diag dot + L2 partial. One wave per row.
// Block 0 also zeroes the combine-stage accumulators/ticket (stream-ordered
// before combine_final; kernel boundary makes it device-visible).
__global__ __launch_bounds__(256) void prep_kernel(const float* __restrict__ A,
                                                   const float* __restrict__ P,
                                                   unsigned short* __restrict__ Abf,
                                                   unsigned short* __restrict__ Pbf,
                                                   float* __restrict__ D,
                                                   float* __restrict__ rowl2,
                                                   float* __restrict__ accL,
                                                   float* __restrict__ accR,
                                                   unsigned int* __restrict__ ticket) {
    if (blockIdx.x == 0 && threadIdx.x == 0) {
        accL[0] = 0.0f; accR[0] = 0.0f; ticket[0] = 0u;
    }
    int t = threadIdx.x;
    int lane = t & 63;
    int row = blockIdx.x * 4 + (t >> 6);
    const float4* a4 = (const float4*)(A + (size_t)row * Dm);
    const float4* p4 = (const float4*)(P + (size_t)row * Dm);
    ushort4* ao = (ushort4*)(Abf + (size_t)row * Dm);
    ushort4* po = (ushort4*)(Pbf + (size_t)row * Dm);
    float dot = 0.0f, l2 = 0.0f;
#pragma unroll
    for (int c = 0; c < 4; ++c) {
        int idx = c * 64 + lane;              // coalesced within the wave
        float4 a = a4[idx], p = p4[idx];
        ushort4 ab, pb;
        ab.x = f2bf(a.x); ab.y = f2bf(a.y); ab.z = f2bf(a.z); ab.w = f2bf(a.w);
        pb.x = f2bf(p.x); pb.y = f2bf(p.y); pb.z = f2bf(p.z); pb.w = f2bf(p.w);
        ao[idx] = ab; po[idx] = pb;
        dot += a.x * p.x + a.y * p.y + a.z * p.z + a.w * p.w;
        l2  += a.x * a.x + a.y * a.y + a.z * a.z + a.w * a.w
             + p.x * p.x + p.y * p.y + p.z * p.z + p.w * p.w;
    }
#pragma unroll
    for (int off = 32; off; off >>= 1) {
        dot += __shfl_xor(dot, off, 64);
        l2  += __shfl_xor(l2,  off, 64);
    }
    if (lane == 0) {
        D[row]     = dot;
        rowl2[row] = l2;
    }
}

// ---------------------------------------------------------------------------
// Kernel 2 (R8 last-known-good, reverted from the failed cooperative fusion):
// 256x256 tile, 8 waves, 4-phase/K-tile, counted vmcnt, XOR-chunk LDS,
// setprio, ph3 j-outer MFMA cluster with interleaved B-refill.
//
// Invariants (hand-verified):
//  vmem queue entering tile t: [B(t+1) x4]; ph0 +A(t+1), ph1/2 +B(t+2) x2+2;
//  ph3 vmcnt(4) completes B(t+1)+A(t+1) BEFORE the barrier; refill reads are
//  pinned below it by sched_barrier(0). t==14: vmcnt(0); t==15: none.
//  LDS WAR separations >=2 barriers. All guards block-uniform.
// ---------------------------------------------------------------------------
#define STAGE_TILE(gp, lp, kt) do {                                            \
        gload_lds16((gp) + (kt),                    (lp)         + tid * 8);   \
        gload_lds16((gp) + (kt) +  64 * (size_t)Dm, (lp) + 4096  + tid * 8);   \
        gload_lds16((gp) + (kt) + 128 * (size_t)Dm, (lp) + 8192  + tid * 8);   \
        gload_lds16((gp) + (kt) + 192 * (size_t)Dm, (lp) + 12288 + tid * 8);   \
    } while (0)

#define STAGE_B_HALF(lpB, kt, h) do {                                          \
        gload_lds16(gB + (kt) + ((h) ? 128 * (size_t)Dm : (size_t)0),          \
                    (lpB) + (h) * 8192 + tid * 8);                             \
        gload_lds16(gB + (kt) + ((h) ? 192 * (size_t)Dm : 64 * (size_t)Dm),    \
                    (lpB) + (h) * 8192 + 4096 + tid * 8);                      \
    } while (0)

#define READ_A4(dst, buf, rg0) do {                                            \
        dst[0] = *(const bf16x8*)((buf) + ((rg0)     * 16) * BK + aoff0);      \
        dst[1] = *(const bf16x8*)((buf) + ((rg0)     * 16) * BK + aoff1);      \
        dst[2] = *(const bf16x8*)((buf) + ((rg0) + 1) * 16 * BK + aoff0);      \
        dst[3] = *(const bf16x8*)((buf) + ((rg0) + 1) * 16 * BK + aoff1);      \
    } while (0)

#define READ_B8(buf) do {                                                      \
        _Pragma("unroll")                                                      \
        for (int j = 0; j < 4; ++j) {                                          \
            bfr[j][0] = *(const bf16x8*)((buf) + j * 16 * BK + aoff0);         \
            bfr[j][1] = *(const bf16x8*)((buf) + j * 16 * BK + aoff1);         \
        }                                                                      \
    } while (0)

#define MFMA_PH(P, ap)                                                         \
    _Pragma("unroll")                                                          \
    for (int j = 0; j < 4; ++j)                                                \
        acc[2*(P)][j]   = __builtin_amdgcn_mfma_f32_16x16x32_bf16(ap[0], bfr[j][0], acc[2*(P)][j],   0, 0, 0); \
    _Pragma("unroll")                                                          \
    for (int j = 0; j < 4; ++j)                                                \
        acc[2*(P)][j]   = __builtin_amdgcn_mfma_f32_16x16x32_bf16(ap[1], bfr[j][1], acc[2*(P)][j],   0, 0, 0); \
    _Pragma("unroll")                                                          \
    for (int j = 0; j < 4; ++j)                                                \
        acc[2*(P)+1][j] = __builtin_amdgcn_mfma_f32_16x16x32_bf16(ap[2], bfr[j][0], acc[2*(P)+1][j], 0, 0, 0); \
    _Pragma("unroll")                                                          \
    for (int j = 0; j < 4; ++j)                                                \
        acc[2*(P)+1][j] = __builtin_amdgcn_mfma_f32_16x16x32_bf16(ap[3], bfr[j][1], acc[2*(P)+1][j], 0, 0, 0);

// ph3 cluster, j-outer: after bfr[j]'s 4th (last) use, refill it for tile NXT.
#define MFMA_PH3_REFILL(ap, bufn, DOREFILL)                                    \
    _Pragma("unroll")                                                          \
    for (int j = 0; j < 4; ++j) {                                              \
        acc[6][j] = __builtin_amdgcn_mfma_f32_16x16x32_bf16(ap[0], bfr[j][0], acc[6][j], 0, 0, 0); \
        acc[6][j] = __builtin_amdgcn_mfma_f32_16x16x32_bf16(ap[1], bfr[j][1], acc[6][j], 0, 0, 0); \
        acc[7][j] = __builtin_amdgcn_mfma_f32_16x16x32_bf16(ap[2], bfr[j][0], acc[7][j], 0, 0, 0); \
        acc[7][j] = __builtin_amdgcn_mfma_f32_16x16x32_bf16(ap[3], bfr[j][1], acc[7][j], 0, 0, 0); \
        if (DOREFILL) {                                                        \
            bfr[j][0] = *(const bf16x8*)((bufn) + j * 16 * BK + aoff0);        \
            bfr[j][1] = *(const bf16x8*)((bufn) + j * 16 * BK + aoff1);        \
        }                                                                      \
    }

#define PHASE_EDGE() do {                                                      \
        __builtin_amdgcn_sched_barrier(0);                                     \
        __builtin_amdgcn_s_barrier();                                          \
        asm volatile("s_waitcnt lgkmcnt(0)" ::: "memory");                     \
        __builtin_amdgcn_sched_barrier(0);                                     \
    } while (0)

#define TILE_BODY(CUR, NXT) do {                                               \
        const unsigned short* aT  = aBase + (CUR) * 16384;                     \
        const unsigned short* aTn = aBase + (NXT) * 16384;                     \
        const unsigned short* bTn = bBase + (NXT) * 16384;                     \
        unsigned short* stA = &As[NXT][0];                                     \
        unsigned short* stB = &Bs[CUR][0];                                     \
        READ_A4(aF[1], aT, 2);                                                 \
        if (t >= 1 && t <= 14) STAGE_TILE(gA, stA, (t + 1) * BK);              \
        __builtin_amdgcn_s_setprio(1);                                         \
        MFMA_PH(0, aF[0])                                                      \
        __builtin_amdgcn_s_setprio(0);                                         \
        PHASE_EDGE();                                                          \
        READ_A4(aF[0], aT, 4);                                                 \
        if (t <= 13) STAGE_B_HALF(stB, (t + 2) * BK, 0);                       \
        __builtin_amdgcn_s_setprio(1);                                         \
        MFMA_PH(1, aF[1])                                                      \
        __builtin_amdgcn_s_setprio(0);                                         \
        PHASE_EDGE();                                                          \
        READ_A4(aF[1], aT, 6);                                                 \
        if (t <= 13) STAGE_B_HALF(stB, (t + 2) * BK, 1);                       \
        __builtin_amdgcn_s_setprio(1);                                         \
        MFMA_PH(2, aF[0])                                                      \
        __builtin_amdgcn_s_setprio(0);                                         \
        PHASE_EDGE();                                                          \
        if (t <= 13)      { asm volatile("s_waitcnt vmcnt(4)" ::: "memory"); } \
        else if (t == 14) { asm volatile("s_waitcnt vmcnt(0)" ::: "memory"); } \
        if (t <= 14) __builtin_amdgcn_s_barrier();                             \
        __builtin_amdgcn_sched_barrier(0);                                     \
        __builtin_amdgcn_s_setprio(1);                                         \
        MFMA_PH3_REFILL(aF[1], bTn, (t <= 14))                                 \
        __builtin_amdgcn_s_setprio(0);                                         \
        if (t <= 14) {                                                         \
            READ_A4(aF[0], aTn, 0);                                            \
            PHASE_EDGE();                                                      \
        }                                                                      \
    } while (0)

__global__ __launch_bounds__(512, 2) void npair_mfma(const unsigned short* __restrict__ Abf,
                                                     const unsigned short* __restrict__ Pbf,
                                                     float* __restrict__ Mpart,
                                                     float* __restrict__ Spart) {
    __shared__ unsigned short As[2][256 * BK];   // 64 KB (double-buffered A tile)
    __shared__ unsigned short Bs[2][256 * BK];   // 64 KB — total 128 KB, 1 block/CU

    int tid = threadIdx.x;
    int lane = tid & 63;
    int wid = tid >> 6;
    int wr = wid >> 2, wc = wid & 3;             // 2x4 waves, each owns 128x64 output

    // XCD-aware bijective swizzle: 256 blocks -> 8 XCDs x 32.
    int bid = blockIdx.y * gridDim.x + blockIdx.x;
    int xcd = bid & 7, lid = bid >> 3;           // lid in [0,32)
    int by = (xcd >> 1) * 4 + (lid >> 3);        // [0,16)
    int bx = (xcd & 1) * 8 + (lid & 7);          // [0,16)
    int row0 = by * 256, col0 = bx * 256;

    // Staging: slot L = row*8 + c holds global k-chunk (c ^ (row&7)); swizzle in
    // the GLOBAL address, LDS dest lane-linear (global_load_lds requirement).
    int srow = tid >> 3;
    int kcol = (tid & 7) ^ (srow & 7);
    const unsigned short* gA = Abf + (size_t)(row0 + srow) * Dm + (kcol << 3);
    const unsigned short* gB = Pbf + (size_t)(col0 + srow) * Dm + (kcol << 3);

    // Prologue: fully stage tiles 0 and 1 (16 vmem instrs), wait oldest 8 (=T0).
    STAGE_TILE(gA, &As[0][0], 0);
    STAGE_TILE(gB, &Bs[0][0], 0);
    STAGE_TILE(gA, &As[1][0], BK);
    STAGE_TILE(gB, &Bs[1][0], BK);
    asm volatile("s_waitcnt vmcnt(8)" ::: "memory");
    __builtin_amdgcn_s_barrier();

    int l15 = lane & 15;
    int aoff0 = (((lane >> 4)    ) ^ (lane & 7)) << 3;   // ks=0 chunk (shorts)
    int aoff1 = (((lane >> 4) + 4) ^ (lane & 7)) << 3;   // ks=1 chunk
    const unsigned short* aBase = &As[0][0] + (wr * 128 + l15) * BK;
    const unsigned short* bBase = &Bs[0][0] + (wc * 64  + l15) * BK;

    f32x4 acc[8][4] = {};
    bf16x8 bfr[4][2];      // B frags, SINGLE buffer (refilled inside ph3 cluster)
    bf16x8 aF[2][4];       // A rowgroup pair, phase-parity ping-pong

    READ_B8(bBase);
    READ_A4(aF[0], aBase, 0);
    __builtin_amdgcn_sched_barrier(0);
    asm volatile("s_waitcnt lgkmcnt(0)" ::: "memory");
    __builtin_amdgcn_sched_barrier(0);

    for (int tt = 0; tt < NT / 2; ++tt) {
        int t = 2 * tt;
        TILE_BODY(0, 1);
        t = 2 * tt + 1;
        TILE_BODY(1, 0);
    }
    __builtin_amdgcn_sched_barrier(0);

    // Epilogue: partials of RAW S (shift-invariant LSE; D applied in combine).
    // C/D layout: col = lane&15, row = (lane>>4)*4 + reg [m89/m91].
    int cb = bx * 4 + wc;
#pragma unroll
    for (int i = 0; i < 8; ++i) {
        int rloc = wr * 128 + i * 16 + ((lane >> 4) << 2);
#pragma unroll
        for (int e = 0; e < 4; ++e) {
            int gr = row0 + rloc + e;
            float xs[4];
            float m = -INFINITY;
#pragma unroll
            for (int j = 0; j < 4; ++j) {
                int gc = col0 + wc * 64 + j * 16 + (lane & 15);
                float x = acc[i][j][e];
                if (gr == gc) x = -INFINITY;      // mask diagonal
                xs[j] = x;
                m = fmaxf(m, x);
            }
#pragma unroll
            for (int off = 8; off; off >>= 1) m = fmaxf(m, __shfl_xor(m, off, 64));
            float s = 0.0f;
#pragma unroll
            for (int j = 0; j < 4; ++j) s += __expf(xs[j] - m);   // exp(-inf)=0 on diag
#pragma unroll
            for (int off = 8; off; off >>= 1) s += __shfl_xor(s, off, 64);
            if ((lane & 15) == 0) {
                Mpart[(size_t)gr * NCB + cb] = m;
                Spart[(size_t)gr * NCB + cb] = s;
            }
        }
    }
}

// Kernel 3 (fused combine+final): per-row LSE over 64 partials, subtract D,
// softplus -> per-block (8-row) partial; device-scope atomicAdd into two
// accumulators; ticketed last block emits the scalar.
__global__ __launch_bounds__(256) void combine_final(const float* __restrict__ Mpart,
                                                     const float* __restrict__ Spart,
                                                     const float* __restrict__ D,
                                                     const float* __restrict__ rowl2,
                                                     float* __restrict__ accL,
                                                     float* __restrict__ accR,
                                                     unsigned int* __restrict__ ticket,
                                                     float* __restrict__ out) {
    int t = threadIdx.x;
    int lane = t & 63;
    int w = t >> 6;
    __shared__ float ls[8];
#pragma unroll
    for (int r = 0; r < 2; ++r) {
        int row = blockIdx.x * 8 + w * 2 + r;
        float mp = Mpart[(size_t)row * NCB + lane];
        float sp = Spart[(size_t)row * NCB + lane];
        float m = mp;
#pragma unroll
        for (int off = 32; off; off >>= 1) m = fmaxf(m, __shfl_xor(m, off, 64));
        float s = sp * __expf(mp - m);
#pragma unroll
        for (int off = 32; off; off >>= 1) s += __shfl_xor(s, off, 64);
        if (lane == 0) {
            float z = m + logf(s) - D[row];              // = LSE_offdiag(S) - D
            ls[w * 2 + r] = fmaxf(z, 0.0f) + log1pf(__expf(-fabsf(z)));  // log1p(e^z)
        }
    }
    __syncthreads();
    if (t == 0) {
        int r8 = blockIdx.x * 8;
        float L = 0.0f, R = 0.0f;
#pragma unroll
        for (int r = 0; r < 8; ++r) { L += ls[r]; R += rowl2[r8 + r]; }
        atomicAdd(accL, L);
        atomicAdd(accR, R);
        __threadfence();
        unsigned int done = atomicAdd(ticket, 1u);
        if (done == NPART - 1) {
            float aL = atomicAdd(accL, 0.0f);   // coherent device-scope read
            float aR = atomicAdd(accR, 0.0f);
            out[0] = aL / (float)N + 0.02f * (aR / (float)N);
        }
    }
}

extern "C" void kernel_launch(void* const* d_in, const int* in_sizes, int n_in,
                              void* d_out, int out_size, void* d_ws, size_t ws_size,
                              hipStream_t stream) {
    const float* A = (const float*)d_in[0];
    const float* P = (const float*)d_in[1];
    float* out = (float*)d_out;

    unsigned short* Abf = (unsigned short*)d_ws;            // N*Dm bf16 = 8 MiB
    unsigned short* Pbf = Abf + (size_t)N * Dm;             // 8 MiB
    float* D     = (float*)(Pbf + (size_t)N * Dm);          // N
    float* rowl2 = D + N;                                   // N
    float* accL  = rowl2 + N;                               // 1
    float* accR  = accL + 1;                                // 1
    unsigned int* ticket = (unsigned int*)(accR + 1);       // 1
    float* Mpart = (float*)(ticket + 1);                    // N*NCB = 1 MiB
    float* Spart = Mpart + (size_t)N * NCB;                 // 1 MiB

    prep_kernel<<<N / 4, 256, 0, stream>>>(A, P, Abf, Pbf, D, rowl2, accL, accR, ticket);
    dim3 grid(16, 16);                                      // 256 blocks = 1/CU
    npair_mfma<<<grid, 512, 0, stream>>>(Abf, Pbf, Mpart, Spart);
    combine_final<<<N / 8, 256, 0, stream>>>(Mpart, Spart, D, rowl2, accL, accR, ticket, out);
}